// Round 1
// 1238.753 us; speedup vs baseline: 1.2912x; 1.2912x over previous
//
#include <hip/hip_runtime.h>
#include <hip/hip_bf16.h>

// SRM constants (match reference: float(np.exp(-1/16)), float(np.exp(-1/4)))
#define DM 0.9394130628134758f
#define DSC 0.7788007830714049f
#define TH 0.3f

#define B 16
#define T 16

typedef short short8 __attribute__((ext_vector_type(8)));
typedef float f32x4 __attribute__((ext_vector_type(4)));

#define SPK1 ((unsigned short)0x3F80)  // bf16 1.0

__device__ __forceinline__ void srm(float& m, float& s, float p, float I, float& spk) {
    m = DM * m * (1.f - p) + I;
    s = DSC * s * (1.f - p) + I;
    spk = (m - s > TH) ? 1.f : 0.f;
}

// ============ weight prep: fp32 OIHW -> 3-term bf16 [term][tap][co][ci] ============
__global__ __launch_bounds__(256) void k_prep(const float* __restrict__ W,
                                              unsigned short* __restrict__ Ws,
                                              int CO, int CI) {
    int idx = blockIdx.x * 256 + threadIdx.x;
    int total = CO * CI * 9;
    if (idx >= total) return;
    int tap = idx % 9, tmp = idx / 9, ci = tmp % CI, co = tmp / CI;
    float w = W[((size_t)co * CI + ci) * 9 + tap];
    __hip_bfloat16 h = __float2bfloat16(w);
    float hf = __bfloat162float(h);
    __hip_bfloat16 mdd = __float2bfloat16(w - hf);
    float mf = __bfloat162float(mdd);
    __hip_bfloat16 lo = __float2bfloat16(w - hf - mf);
    size_t base = ((size_t)tap * CO + co) * CI + ci;
    size_t stride = (size_t)9 * CO * CI;
    Ws[base] = *(unsigned short*)&h;
    Ws[base + stride] = *(unsigned short*)&mdd;
    Ws[base + 2 * stride] = *(unsigned short*)&lo;
}

// ============ conv0T: all 16 steps, state in regs -> s0b_all [t][b][y][x][64ci] bf16 ====
// grid: 16b*8yt*8cog = 1024 blocks, 128 thr.
#define S0 68
__global__ __launch_bounds__(128) void k_conv0T(const float* __restrict__ in,
                                                const float* __restrict__ W0,
                                                unsigned short* __restrict__ s0b) {
    __shared__ float tile[2][10 * S0];
    int bid = blockIdx.x;
    int cog = bid & 7, yt = (bid >> 3) & 7, b = bid >> 6;
    int tid = threadIdx.x;
    int tx = (tid & 15) * 4, ty = tid >> 4;   // ty 0..7
    int y0 = yt * 8, y = y0 + ty;

    float m[8][4] = {}, s[8][4] = {};
    unsigned pmask = 0;                        // bit c*4+j

    for (int t = 0; t < T; t++) {
        if (t) __syncthreads();
        for (int i = tid; i < 2 * 660; i += 128) {
            int cl = i / 660, rem = i - cl * 660;
            int r = rem / 66, c = rem - r * 66;
            int gy = y0 + r - 1, gx = c - 1;
            float v = 0.f;
            if ((unsigned)gy < 64u && (unsigned)gx < 64u) {
                const float* src = in + ((size_t)((b * T + t) * 2 + cl)) * 4096;
                v = fminf(fmaxf(src[gy * 64 + gx], 0.f), 1.f);
            }
            tile[cl][r * S0 + c] = v;
        }
        __syncthreads();

        float acc[8][4] = {};
#pragma unroll
        for (int cl = 0; cl < 2; cl++) {
            const float* wb = W0 + ((size_t)cog * 8 * 2 + cl) * 9;
#pragma unroll
            for (int dy = 0; dy < 3; dy++) {
                float4 A = *(const float4*)&tile[cl][(ty + dy) * S0 + tx];
                float4 Bv = *(const float4*)&tile[cl][(ty + dy) * S0 + tx + 4];
                float r0 = A.x, r1 = A.y, r2 = A.z, r3 = A.w, r4 = Bv.x, r5 = Bv.y;
#pragma unroll
                for (int c = 0; c < 8; c++) {
                    const float* w = wb + (size_t)c * 2 * 9 + dy * 3;
                    float wa = w[0], wbx = w[1], wc = w[2];
                    acc[c][0] += wa * r0 + wbx * r1 + wc * r2;
                    acc[c][1] += wa * r1 + wbx * r2 + wc * r3;
                    acc[c][2] += wa * r2 + wbx * r3 + wc * r4;
                    acc[c][3] += wa * r3 + wbx * r4 + wc * r5;
                }
            }
        }

        unsigned newmask = 0;
        unsigned short* s0p = s0b + ((size_t)(t * 16 + b) * 4096) * 64;
#pragma unroll
        for (int j = 0; j < 4; j++) {
            short8 sv;
#pragma unroll
            for (int c = 0; c < 8; c++) {
                int bit = c * 4 + j;
                float p = (pmask >> bit) & 1 ? 1.f : 0.f;
                float spk;
                srm(m[c][j], s[c][j], p, acc[c][j], spk);
                bool on = spk > 0.5f;
                if (on) newmask |= 1u << bit;
                sv[c] = on ? (short)SPK1 : (short)0;
            }
            *(short8*)(s0p + ((size_t)(y * 64 + tx + j)) * 64 + cog * 8) = sv;
        }
        pmask = newmask;
    }
}

// ============ conv1T MFMA v2: 512 thr (8 waves, 2/SIMD), two batches per block ======
// Block: 16 co x 8 rows x 64 x, for batches b=xcd and b=xcd+8 (one 256-thr group each).
// A-tile staged in 2 kc-phases (32 ci each): per-group atile [4c][10r][66x] = 42,240 B.
// LDS = 2*42,240 + 55,296 (wlds, shared) = 139,776 B -> 1 block/CU, 8 waves = 2/SIMD.
// MFMA order (kc -> dy -> dx -> tm) identical to v1 -> bit-exact.
__global__ __launch_bounds__(512, 2) void k_conv1T(const unsigned short* __restrict__ s0b,
                                                   const unsigned short* __restrict__ W1s,
                                                   unsigned short* __restrict__ p1b) {
    __shared__ short8 atile[2][2640];   // [grp][c*660 + r*66 + x]
    __shared__ short8 wlds[3456];
    int bid = blockIdx.x;               // 512 blocks: 8 xcd x 8 yq x 8 cog
    int xcd = bid & 7;
    int yq = (bid >> 3) & 7;
    int cog = bid >> 6;
    int tid = threadIdx.x;              // 0..511
    int grp = tid >> 8;                 // 0 -> batch xcd, 1 -> batch xcd+8
    int t8 = tid & 255;
    int b = xcd + grp * 8;
    int lane = tid & 63, wv = (t8 >> 6);  // wave-in-group 0..3
    int n = lane & 15, q = lane >> 4;
    int y0 = yq * 8;

    const short8 zf = {0, 0, 0, 0, 0, 0, 0, 0};
    // zero both A-tiles once (halo cells stay zero forever)
    for (int i = tid; i < 5280; i += 512) ((short8*)atile)[i] = zf;
    for (int idx = tid; idx < 3456; idx += 512) {
        int nn = idx & 15, qq = (idx >> 4) & 3;
        int rem = idx >> 6;                     // (kc*9+tap)*3+tm
        int tm = rem % 3, rem2 = rem / 3;
        int tap = rem2 % 9, kc = rem2 / 9;
        wlds[idx] = *(const short8*)(W1s +
            ((size_t)(tm * 9 + tap) * 128 + cog * 16 + nn) * 64 + kc * 32 + qq * 8);
    }

    int yr = yq * 4 + wv;
    int co = cog * 16 + n;

    float sm[2][4][4] = {}, ss[2][4][4] = {};
    unsigned pmask = 0;                         // bit (yo*4+xt)*4 + r

    for (int t = 0; t < T; t++) {
        const unsigned short* sb = s0b + ((size_t)(t * 16 + b) * 4096) * 64;

        f32x4 acc[2][4];
#pragma unroll
        for (int i = 0; i < 2; i++)
#pragma unroll
            for (int j = 0; j < 4; j++) acc[i][j] = (f32x4){0.f, 0.f, 0.f, 0.f};

#pragma unroll
        for (int kc = 0; kc < 2; kc++) {
            __syncthreads();   // prev phase compute done; init/wlds visible
            // stage this kc's 32 ci (4 chunks) for this group's batch
            for (int i = t8; i < 2560; i += 256) {
                int c = i & 3, x64 = (i >> 2) & 63, r = i >> 8;   // r wave-uniform
                int gy = y0 - 1 + r;
                if ((unsigned)gy < 64u) {
                    short8 v = *(const short8*)(sb + ((size_t)(gy * 64 + x64)) * 64 + (kc * 4 + c) * 8);
                    atile[grp][c * 660 + r * 66 + x64 + 1] = v;
                }
            }
            __syncthreads();

            int cbase = q * 660;
#pragma unroll
            for (int dy = 0; dy < 3; dy++) {
                int rA = wv * 2 + dy, rB = rA + 1;   // tile rows (OOB rows are zeros)
#pragma unroll
                for (int dx = 0; dx < 3; dx++) {
                    int tap = dy * 3 + dx;
                    short8 AfA[4], AfB[4];
#pragma unroll
                    for (int xt = 0; xt < 4; xt++) {
                        int x = xt * 16 + n + dx;    // tile x (halo baked)
                        AfA[xt] = atile[grp][cbase + rA * 66 + x];
                        AfB[xt] = atile[grp][cbase + rB * 66 + x];
                    }
#pragma unroll
                    for (int tm = 0; tm < 3; tm++) {
                        short8 Bf = wlds[((kc * 9 + tap) * 3 + tm) * 64 + q * 16 + n];
#pragma unroll
                        for (int xt = 0; xt < 4; xt++) {
                            acc[0][xt] = __builtin_amdgcn_mfma_f32_16x16x32_bf16(AfA[xt], Bf, acc[0][xt], 0, 0, 0);
                            acc[1][xt] = __builtin_amdgcn_mfma_f32_16x16x32_bf16(AfB[xt], Bf, acc[1][xt], 0, 0, 0);
                        }
                    }
                }
            }
        }

        unsigned newmask = 0;
#pragma unroll
        for (int yo = 0; yo < 2; yo++)
#pragma unroll
            for (int xt = 0; xt < 4; xt++)
#pragma unroll
                for (int r = 0; r < 4; r++) {
                    int bit = (yo * 4 + xt) * 4 + r;
                    float p = (pmask >> bit) & 1 ? 1.f : 0.f;
                    float spk;
                    srm(sm[yo][xt][r], ss[yo][xt][r], p, acc[yo][xt][r], spk);
                    if (spk > 0.5f) newmask |= 1u << bit;
                }
        pmask = newmask;

        unsigned short* pb = p1b + (((size_t)(t * 16 + b) * 1024) + yr * 32) * 128 + co;
#pragma unroll
        for (int xt = 0; xt < 4; xt++)
#pragma unroll
            for (int rp = 0; rp < 2; rp++) {
                int i0 = (0 * 4 + xt) * 4 + 2 * rp;
                int i1 = (1 * 4 + xt) * 4 + 2 * rp;
                unsigned on = ((newmask >> i0) | (newmask >> (i0 + 1)) |
                               (newmask >> i1) | (newmask >> (i1 + 1))) & 1u;
                int xp = xt * 8 + q * 2 + rp;
                pb[(size_t)xp * 128] = on ? SPK1 : (unsigned short)0;
            }
    }
}

// ============ conv2T MFMA v2: 512 thr (8 waves, 2/SIMD), 16 rows per block ==========
// Block: 16 co x 16 rows x 32 x. A-tile staged in 4 kc-phases (32 ci each):
// atile [4c][18r][34x] = 39,168 B; wlds 110,592 B -> 149,760 B total, 8 waves = 2/SIMD.
// MFMA order (kc 0..3 -> dy -> dx -> tm) identical to v1 -> bit-exact.
__global__ __launch_bounds__(512, 2) void k_conv2T(const unsigned short* __restrict__ p1b,
                                                   const unsigned short* __restrict__ W2s,
                                                   float* __restrict__ p2) {
    __shared__ short8 atile[2448];      // c*612 + r*34 + x
    __shared__ short8 wlds[6912];
    int bid = blockIdx.x;               // 256 blocks
    int xcd = bid & 7, rest = bid >> 3; // rest 0..31
    int b = ((rest & 1) << 3) | xcd;
    int yh = (rest >> 1) & 1;
    int cog = (rest >> 2) & 7;
    int tid = threadIdx.x;              // 0..511
    int lane = tid & 63, wv = tid >> 6; // 0..7
    int n = lane & 15, q = lane >> 4;
    int y0 = yh * 16;

    const short8 zf = {0, 0, 0, 0, 0, 0, 0, 0};
    for (int i = tid; i < 2448; i += 512) atile[i] = zf;
    for (int idx = tid; idx < 6912; idx += 512) {
        int nn = idx & 15, qq = (idx >> 4) & 3;
        int rem = idx >> 6;                     // (kc*9+tap)*3+tm
        int tm = rem % 3, rem2 = rem / 3;
        int tap = rem2 % 9, kc = rem2 / 9;
        wlds[idx] = *(const short8*)(W2s +
            ((size_t)(tm * 9 + tap) * 128 + cog * 16 + nn) * 128 + kc * 32 + qq * 8);
    }

    int yr = yh * 8 + wv;
    int co = cog * 16 + n;

    float sm[2][2][4] = {}, ss[2][2][4] = {};
    unsigned pmask = 0;                         // bit (yo*2+xt)*4 + r

    for (int t = 0; t < T; t++) {
        const unsigned short* sb = p1b + ((size_t)(t * 16 + b) * 1024) * 128;
        f32x4 acc[2][2];
#pragma unroll
        for (int i = 0; i < 2; i++)
#pragma unroll
            for (int j = 0; j < 2; j++) acc[i][j] = (f32x4){0.f, 0.f, 0.f, 0.f};

#pragma unroll
        for (int kc = 0; kc < 4; kc++) {
            __syncthreads();   // prev phase compute done before restaging
            for (int i = tid; i < 2304; i += 512) {
                int c = i & 3, x32 = (i >> 2) & 31, r = i >> 7;   // r wave-uniform
                int gy = y0 - 1 + r;
                if ((unsigned)gy < 32u) {
                    short8 v = *(const short8*)(sb + ((size_t)(gy * 32 + x32)) * 128 + (kc * 4 + c) * 8);
                    atile[c * 612 + r * 34 + x32 + 1] = v;
                }
            }
            __syncthreads();

            int cbase = q * 612;
#pragma unroll
            for (int dy = 0; dy < 3; dy++) {
                int rA = wv * 2 + dy, rB = rA + 1;   // up to 17, within 18 rows
#pragma unroll
                for (int dx = 0; dx < 3; dx++) {
                    int tap = dy * 3 + dx;
                    short8 AfA[2], AfB[2];
#pragma unroll
                    for (int xt = 0; xt < 2; xt++) {
                        int x = xt * 16 + n + dx;
                        AfA[xt] = atile[cbase + rA * 34 + x];
                        AfB[xt] = atile[cbase + rB * 34 + x];
                    }
#pragma unroll
                    for (int tm = 0; tm < 3; tm++) {
                        short8 Bf = wlds[((kc * 9 + tap) * 3 + tm) * 64 + q * 16 + n];
#pragma unroll
                        for (int xt = 0; xt < 2; xt++) {
                            acc[0][xt] = __builtin_amdgcn_mfma_f32_16x16x32_bf16(AfA[xt], Bf, acc[0][xt], 0, 0, 0);
                            acc[1][xt] = __builtin_amdgcn_mfma_f32_16x16x32_bf16(AfB[xt], Bf, acc[1][xt], 0, 0, 0);
                        }
                    }
                }
            }
        }

        unsigned newmask = 0;
#pragma unroll
        for (int yo = 0; yo < 2; yo++)
#pragma unroll
            for (int xt = 0; xt < 2; xt++)
#pragma unroll
                for (int r = 0; r < 4; r++) {
                    int bit = (yo * 2 + xt) * 4 + r;
                    float p = (pmask >> bit) & 1 ? 1.f : 0.f;
                    float spk;
                    srm(sm[yo][xt][r], ss[yo][xt][r], p, acc[yo][xt][r], spk);
                    if (spk > 0.5f) newmask |= 1u << bit;
                }
        pmask = newmask;

        float* pp = p2 + (size_t)(t * 16 + b) * 32768 + (size_t)co * 256 + yr * 16;
#pragma unroll
        for (int xt = 0; xt < 2; xt++)
#pragma unroll
            for (int rp = 0; rp < 2; rp++) {
                int i0 = (0 * 2 + xt) * 4 + 2 * rp;
                int i1 = (1 * 2 + xt) * 4 + 2 * rp;
                unsigned on = ((newmask >> i0) | (newmask >> (i0 + 1)) |
                               (newmask >> i1) | (newmask >> (i1 + 1))) & 1u;
                int xp = xt * 8 + q * 2 + rp;
                pp[xp] = on ? 1.f : 0.f;
            }
    }
}

// ============ fc3: per-t grid. p2[t][16,32768] @ W3^T -> I3p[t][ks][8192] ============
// grid 8192 = 32 ot x 16 ks x 16 t; block 256 (4 waves). Wave: 4 o x 16 b, lanes along k.
__global__ __launch_bounds__(256) void k_fc3(const float* __restrict__ p2,
                                             const float* __restrict__ W3,
                                             float* __restrict__ I3p) {
    int ot = blockIdx.x & 31, ks = (blockIdx.x >> 5) & 15, t = blockIdx.x >> 9;
    int lane = threadIdx.x & 63, wv = threadIdx.x >> 6;
    int o0 = ot * 16 + wv * 4;
    int kb = ks * 2048 + lane * 4;

    float acc[4][16];
#pragma unroll
    for (int o = 0; o < 4; o++)
#pragma unroll
        for (int bb = 0; bb < 16; bb++) acc[o][bb] = 0.f;

#pragma unroll
    for (int kk = 0; kk < 8; kk++) {
        int k = kb + kk * 256;
        float4 w4[4];
#pragma unroll
        for (int o = 0; o < 4; o++)
            w4[o] = *(const float4*)(W3 + (size_t)(o0 + o) * 32768 + k);
#pragma unroll
        for (int bb = 0; bb < 16; bb++) {
            float4 pv = *(const float4*)(p2 + (size_t)(t * 16 + bb) * 32768 + k);
#pragma unroll
            for (int o = 0; o < 4; o++)
                acc[o][bb] += w4[o].x * pv.x + w4[o].y * pv.y +
                              w4[o].z * pv.z + w4[o].w * pv.w;
        }
    }
#pragma unroll
    for (int o = 0; o < 4; o++)
#pragma unroll
        for (int bb = 0; bb < 16; bb++)
#pragma unroll
            for (int d = 1; d < 64; d <<= 1)
                acc[o][bb] += __shfl_xor(acc[o][bb], d);

    int bb = lane & 15, osl = lane >> 4;
    float v = 0.f;
#pragma unroll
    for (int o = 0; o < 4; o++)
#pragma unroll
        for (int b2 = 0; b2 < 16; b2++)
            if (osl == o && bb == b2) v = acc[o][b2];
    I3p[((size_t)(t * 16 + ks)) * 8192 + bb * 512 + o0 + osl] = v;
}

// ============ srm3T: per neuron, scan t: reduce 16 partials + SRM -> sp3_all [t][8192]
__global__ __launch_bounds__(256) void k_srm3T(const float* __restrict__ I3p,
                                               float* __restrict__ sp3) {
    int idx = blockIdx.x * 256 + threadIdx.x;    // 8192
    float m = 0.f, s = 0.f, p = 0.f;
    for (int t = 0; t < T; t++) {
        float I = 0.f;
#pragma unroll
        for (int ks = 0; ks < 16; ks++) I += I3p[((size_t)(t * 16 + ks)) * 8192 + idx];
        float spk;
        srm(m, s, p, I, spk);
        p = spk;
        sp3[t * 8192 + idx] = spk;
    }
}

// ============ fc4g: I4[t*16+b][11] = sp3[t][b] @ W4^T ============
__global__ __launch_bounds__(256) void k_fc4g(const float* __restrict__ sp3,
                                              const float* __restrict__ W4,
                                              float* __restrict__ I4) {
    int t = blockIdx.x, tid = threadIdx.x;
    if (tid >= 176) return;
    int b = tid / 11, o = tid - b * 11;
    const float4* a = (const float4*)(sp3 + (size_t)t * 8192 + b * 512);
    const float4* w = (const float4*)(W4 + o * 512);
    float acc = 0.f;
    for (int k = 0; k < 128; k++) {
        float4 x = a[k], y = w[k];
        acc += x.x * y.x + x.y * y.y + x.z * y.z + x.w * y.w;
    }
    I4[(size_t)(t * 16 + b) * 11 + o] = acc;
}

// ============ fc4s: scan t with SRM, write out ============
__global__ __launch_bounds__(256) void k_fc4s(const float* __restrict__ I4,
                                              float* __restrict__ out) {
    int tid = threadIdx.x;
    if (tid >= 176) return;
    int b = tid / 11, o = tid - b * 11;
    float m = 0.f, s = 0.f, p = 0.f, sum = 0.f;
    for (int t = 0; t < T; t++) {
        float I = I4[(size_t)(t * 16 + b) * 11 + o];
        float spk;
        srm(m, s, p, I, spk);
        p = spk;
        sum += spk;
    }
    out[tid] = sum * 0.0625f;   // exact: integer count / 16
}

extern "C" void kernel_launch(void* const* d_in, const int* in_sizes, int n_in,
                              void* d_out, int out_size, void* d_ws, size_t ws_size,
                              hipStream_t stream) {
    const float* in = (const float*)d_in[0];
    const float* W0 = (const float*)d_in[1];
    const float* W1 = (const float*)d_in[2];
    const float* W2 = (const float*)d_in[3];
    const float* W3 = (const float*)d_in[4];
    const float* W4 = (const float*)d_in[5];
    float* out = (float*)d_out;
    char* ws = (char*)d_ws;

    size_t off = 0;
    auto alloc = [&](size_t bytes) {
        void* p = ws + off;
        off += (bytes + 255) & ~(size_t)255;
        return p;
    };
    // all buffers fully written before read each launch -> no memsets needed
    unsigned short* s0b = (unsigned short*)alloc((size_t)256 * 4096 * 64 * 2);   // 134.2 MB
    unsigned short* p1b = (unsigned short*)alloc((size_t)256 * 1024 * 128 * 2);  // 67.1 MB
    float* p2  = (float*)alloc((size_t)256 * 32768 * 4);                          // 33.6 MB
    float* I3p = (float*)alloc((size_t)256 * 8192 * 4);                           // 8.4 MB
    float* sp3 = (float*)alloc((size_t)16 * 8192 * 4);
    float* I4  = (float*)alloc((size_t)256 * 11 * 4);
    unsigned short* W1s = (unsigned short*)alloc((size_t)3 * 9 * 128 * 64 * 2);
    unsigned short* W2s = (unsigned short*)alloc((size_t)3 * 9 * 128 * 128 * 2);

    k_prep<<<(9 * 128 * 64 + 255) / 256, 256, 0, stream>>>(W1, W1s, 128, 64);
    k_prep<<<(9 * 128 * 128 + 255) / 256, 256, 0, stream>>>(W2, W2s, 128, 128);

    k_conv0T<<<16 * 8 * 8, 128, 0, stream>>>(in, W0, s0b);
    k_conv1T<<<512, 512, 0, stream>>>(s0b, W1s, p1b);
    k_conv2T<<<256, 512, 0, stream>>>(p1b, W2s, p2);
    k_fc3<<<32 * 16 * 16, 256, 0, stream>>>(p2, W3, I3p);
    k_srm3T<<<8192 / 256, 256, 0, stream>>>(I3p, sp3);
    k_fc4g<<<16, 256, 0, stream>>>(sp3, W4, I4);
    k_fc4s<<<1, 256, 0, stream>>>(I4, out);
}